// Round 15
// baseline (57.525 us; speedup 1.0000x reference)
//
#include <hip/hip_runtime.h>
#include <math.h>

#define NB 8192
#define ND 128
#define NT 64        // number of 128-row tiles
#define NTRI 2080    // NT*(NT+1)/2 upper-triangle tile pairs
#define NLAB 512
#define MAXM 64

typedef unsigned short u16;
typedef unsigned int u32;
typedef __attribute__((ext_vector_type(8))) short bf16x8;
typedef __attribute__((ext_vector_type(4))) float f32x4;

#define G2 369.3299304675746f         // gamma * log2(e)
#define NEG_C (-23.083120654223414f)  // -G2/16
#define SENT (-1e30f)
#define LN2F 0.6931471805599453f

static __device__ __forceinline__ float fexp2(float x) {
  return __builtin_amdgcn_exp2f(x);
}

static __device__ __forceinline__ u32 f2bf(float f) {
  u32 u = __float_as_uint(f);
  return (u + 0x7FFF + ((u >> 16) & 1)) >> 16;   // RNE
}

static __device__ __forceinline__ float wave_sum_f(float v) {
  #pragma unroll
  for (int off = 1; off < 64; off <<= 1) v += __shfl_xor(v, off);
  return v;
}

// Canonical per-row norm tree: lane partial = sum over ks(asc), j(asc) of
// x[ks*32 + g*8 + j]^2; combine partners via two xor-shuffles -> (P0+P1)+(P2+P3).
// ALL paths (triangle A, B staging, pos) use this exact tree -> the bf16 cast
// of every row is bit-identical everywhere, so same-label negative corrections
// cancel exactly.
static __device__ __forceinline__ void load32(const float* __restrict__ src,
                                              int g, float v[32]) {
  #pragma unroll
  for (int ks = 0; ks < 4; ++ks) {
    const float4 a = *(const float4*)(src + ks * 32 + g * 8);
    const float4 b = *(const float4*)(src + ks * 32 + g * 8 + 4);
    v[ks * 8 + 0] = a.x; v[ks * 8 + 1] = a.y; v[ks * 8 + 2] = a.z; v[ks * 8 + 3] = a.w;
    v[ks * 8 + 4] = b.x; v[ks * 8 + 5] = b.y; v[ks * 8 + 6] = b.z; v[ks * 8 + 7] = b.w;
  }
}

static __device__ __forceinline__ float inv_from_ss(float ss, int o1, int o2) {
  ss += __shfl_xor(ss, o1);
  ss += __shfl_xor(ss, o2);
  return 1.0f / fmaxf(sqrtf(ss), 1e-12f);
}

static __device__ __forceinline__ float ss32(const float v[32]) {
  float ss = 0.f;
  #pragma unroll
  for (int j = 0; j < 32; ++j) ss = fmaf(v[j], v[j], ss);
  return ss;
}

// normalize + pack one row's 4 fragments (partners at xor o1,o2)
static __device__ __forceinline__ void norm_frags(const float* __restrict__ src,
                                                  int g, int o1, int o2,
                                                  bf16x8 out[4]) {
  float v[32];
  load32(src, g, v);
  const float inv = inv_from_ss(ss32(v), o1, o2);
  #pragma unroll
  for (int ks = 0; ks < 4; ++ks) {
    u32 wd[4];
    #pragma unroll
    for (int p = 0; p < 4; ++p)
      wd[p] = f2bf(v[ks * 8 + 2 * p] * inv) | (f2bf(v[ks * 8 + 2 * p + 1] * inv) << 16);
    bf16x8 f;
    #pragma unroll
    for (int p = 0; p < 4; ++p) ((u32*)&f)[p] = wd[p];
    out[ks] = f;
  }
}

// ---- k1: triangle tiles | per-label pos; normalization fused (no prep pass)
__global__ __launch_bounds__(256, 3) void k_mainpos(const float* __restrict__ emb,
                                                    const int* __restrict__ labels,
                                                    float* __restrict__ part,
                                                    float* __restrict__ poscorr) {
  __shared__ __align__(16) char S[33792];   // B tiles / labels+memL / colbuf
  const int bid = blockIdx.x;
  const int tid = threadIdx.x;
  const int l = tid & 63;
  const int w = tid >> 6;
  const int lr_ = l & 15;
  const int lg = l >> 4;

  if (bid < NTRI) {
    // ================= triangle sim tiles (self-normalizing) ===============
    int ti = (int)((129.0f - sqrtf(16641.0f - 8.0f * (float)bid)) * 0.5f);
    if (ti > NT - 1) ti = NT - 1;
    if (ti < 0) ti = 0;
    #define PRE(t) ((t) * NT - ((t) * ((t) - 1)) / 2)
    while (PRE(ti + 1) <= bid) ++ti;
    while (PRE(ti) > bid) --ti;
    const int tj = ti + (bid - PRE(ti));
    #undef PRE
    const int row0 = ti * 128;
    const int col0 = tj * 128;
    const bool diag = (ti == tj);

    // B staging: thread (srow=tid>>2, q=tid&3) normalizes its 8-col slices of
    // row col0+h*64+srow and writes swizzled 16B chunks (global slot s at LDS
    // slot s^(srow&15) -> same invariant as the old gload16 path).
    {
      const int srow = tid >> 2;
      const int q = tid & 3;
      #pragma unroll
      for (int h = 0; h < 2; ++h) {
        const float* src = emb + (size_t)(col0 + h * 64 + srow) * ND;
        float v[32];
        load32(src, q, v);
        const float inv = inv_from_ss(ss32(v), 1, 2);
        #pragma unroll
        for (int ks = 0; ks < 4; ++ks) {
          uint4 wd;
          wd.x = f2bf(v[ks * 8 + 0] * inv) | (f2bf(v[ks * 8 + 1] * inv) << 16);
          wd.y = f2bf(v[ks * 8 + 2] * inv) | (f2bf(v[ks * 8 + 3] * inv) << 16);
          wd.z = f2bf(v[ks * 8 + 4] * inv) | (f2bf(v[ks * 8 + 5] * inv) << 16);
          wd.w = f2bf(v[ks * 8 + 6] * inv) | (f2bf(v[ks * 8 + 7] * inv) << 16);
          char* dst = S + h * 16384 + srow * 256 + (((ks * 4 + q) ^ (srow & 15)) * 16);
          *(uint4*)dst = wd;
        }
      }
    }

    // A fragments: normalize rows row0 + w*32 + m*16 + lr_ (partners = lg)
    bf16x8 af[2][4];
    #pragma unroll
    for (int m = 0; m < 2; ++m)
      norm_frags(emb + (size_t)(row0 + w * 32 + m * 16 + lr_) * ND, lg, 16, 32, af[m]);

    float sn[8], colp[8];
    #pragma unroll
    for (int q = 0; q < 8; ++q) { sn[q] = 0.f; colp[q] = 0.f; }

    __syncthreads();   // both B halves staged

    #pragma unroll
    for (int h = 0; h < 2; ++h) {
      const char* Bh = S + h * 16384;
      f32x4 acc[2][4];
      #pragma unroll
      for (int m = 0; m < 2; ++m)
        #pragma unroll
        for (int n = 0; n < 4; ++n)
          #pragma unroll
          for (int q = 0; q < 4; ++q) acc[m][n][q] = 0.f;

      #pragma unroll
      for (int ks = 0; ks < 4; ++ks) {
        const int kslot = (ks * 4 + lg) ^ lr_;   // read-side swizzle
        bf16x8 bfr[4];
        #pragma unroll
        for (int n = 0; n < 4; ++n)
          bfr[n] = *(const bf16x8*)(Bh + (n * 16 + lr_) * 256 + kslot * 16);
        #pragma unroll
        for (int m = 0; m < 2; ++m)
          #pragma unroll
          for (int n = 0; n < 4; ++n)
            acc[m][n] = __builtin_amdgcn_mfma_f32_16x16x32_bf16(af[m][ks], bfr[n],
                                                                acc[m][n], 0, 0, 0);
      }

      // epilogue: ev feeds row sums and (by symmetry) column sums
      #pragma unroll
      for (int m = 0; m < 2; ++m) {
        #pragma unroll
        for (int n = 0; n < 4; ++n) {
          const bool dmn = diag && (w * 32 + m * 16 == h * 64 + n * 16);
          float scc = 0.f;
          #pragma unroll
          for (int j = 0; j < 4; ++j) {
            const float sv = acc[m][n][j];
            float xn = fmaf(sv * sv, G2, NEG_C);
            xn = (sv > -0.25f) ? xn : 0.f;
            if (dmn) xn = (lr_ == lg * 4 + j) ? SENT : xn;  // drop true diagonal
            const float ev = fexp2(xn);
            sn[m * 4 + j] += ev;
            scc += ev;
          }
          colp[h * 4 + n] += scc;
        }
      }
    }

    // row sums: reduce over 16 column-lanes, write slot tj (coalesced)
    #pragma unroll
    for (int q = 0; q < 8; ++q) {
      #pragma unroll
      for (int off = 1; off < 16; off <<= 1) sn[q] += __shfl_xor(sn[q], off);
    }
    if (lr_ == 0) {
      #pragma unroll
      for (int m = 0; m < 2; ++m)
        #pragma unroll
        for (int j = 0; j < 4; ++j) {
          const int row = row0 + w * 32 + m * 16 + lg * 4 + j;
          part[(size_t)tj * NB + row] = sn[m * 4 + j];
        }
    }

    // column sums (non-diag): reduce lg groups, cross-wave via LDS
    if (!diag) {
      #pragma unroll
      for (int q = 0; q < 8; ++q) {
        colp[q] += __shfl_xor(colp[q], 16);
        colp[q] += __shfl_xor(colp[q], 32);
      }
      __syncthreads();                   // all MFMA LDS reads done
      float* colbuf = (float*)S;
      if (l < 16) {
        #pragma unroll
        for (int q = 0; q < 8; ++q)
          colbuf[w * 128 + (q >> 2) * 64 + (q & 3) * 16 + lr_] = colp[q];
      }
      __syncthreads();
      if (tid < 128) {
        const float cs_ = colbuf[tid] + colbuf[128 + tid] +
                          colbuf[256 + tid] + colbuf[384 + tid];
        part[(size_t)ti * NB + col0 + tid] = cs_;   // 128 consecutive floats
      }
    }
  } else {
    // ================= per-label positives + same-label correction =========
    int* lab = (int*)S;                        // 8192 ints = 32 KB
    for (int i = tid; i < NB / 4; i += 256)
      ((int4*)lab)[i] = ((const int4*)labels)[i];
    __syncthreads();

    const int L = (bid - NTRI) * 4 + w;        // one wave per label
    int* memL = (int*)(S + 32768) + w * MAXM;

    // build ordered member list via ballot rounds (ascending index order)
    int cnt = 0;
    for (int base = 0; base < NB; base += 64) {
      const int lv = lab[base + l];
      const unsigned long long mk = __ballot(lv == L);
      if (lv == L) {
        const int pos = __popcll(mk & ((1ull << l) - 1));
        if (cnt + pos < MAXM) memL[cnt + pos] = base + l;
      }
      cnt += __popcll(mk);
    }
    int c = cnt > MAXM ? MAXM : cnt;
    __syncthreads();   // memL visible across lanes of each wave

    const int nt = (c + 15) >> 4;
    for (int rb = 0; rb < nt; ++rb) {
      const int ri = rb * 16 + lr_;            // uniform across lg partners
      bf16x8 af[4];
      if (ri < c) {
        norm_frags(emb + (size_t)memL[ri] * ND, lg, 16, 32, af);
      } else {
        #pragma unroll
        for (int ks = 0; ks < 4; ++ks) af[ks] = (bf16x8)0;
      }
      float corr[4], mp[4], sp[4];
      #pragma unroll
      for (int r = 0; r < 4; ++r) { corr[r] = 0.f; mp[r] = SENT; sp[r] = 0.f; }

      for (int cb = 0; cb < nt; ++cb) {
        const int ci = cb * 16 + lr_;          // uniform across lg partners
        bf16x8 bfr[4];
        if (ci < c) {
          norm_frags(emb + (size_t)memL[ci] * ND, lg, 16, 32, bfr);
        } else {
          #pragma unroll
          for (int ks = 0; ks < 4; ++ks) bfr[ks] = (bf16x8)0;
        }
        f32x4 acc;
        #pragma unroll
        for (int r = 0; r < 4; ++r) acc[r] = 0.f;
        #pragma unroll
        for (int ks = 0; ks < 4; ++ks)
          acc = __builtin_amdgcn_mfma_f32_16x16x32_bf16(af[ks], bfr[ks], acc, 0, 0, 0);

        #pragma unroll
        for (int r = 0; r < 4; ++r) {
          const int R = rb * 16 + lg * 4 + r;
          const int Cj = cb * 16 + lr_;
          const bool ok = (R < c) && (Cj < c) && (R != Cj);
          const float sv = acc[r];
          float xn = fmaf(sv * sv, G2, NEG_C);
          xn = (sv > -0.25f) ? xn : 0.f;
          corr[r] += ok ? fexp2(xn) : 0.f;
          if (ok) {
            const float t1 = 1.25f - sv;
            const float xp = G2 * fmaxf(t1, 0.f) * (t1 - 0.5f);
            if (xp > mp[r]) { sp[r] = sp[r] * fexp2(mp[r] - xp) + 1.f; mp[r] = xp; }
            else sp[r] += fexp2(xp - mp[r]);
          }
        }
      }
      #pragma unroll
      for (int r = 0; r < 4; ++r) {
        #pragma unroll
        for (int off = 1; off < 16; off <<= 1) {
          corr[r] += __shfl_xor(corr[r], off);
          const float m2 = __shfl_xor(mp[r], off), s2 = __shfl_xor(sp[r], off);
          const float M = fmaxf(mp[r], m2);
          const float t1 = sp[r] * fexp2(mp[r] - M);  // exp2(-1e30)=0 for empties
          const float t2 = s2 * fexp2(m2 - M);
          mp[r] = M; sp[r] = t1 + t2;
        }
      }
      if (lr_ == 0) {
        #pragma unroll
        for (int r = 0; r < 4; ++r) {
          const int R = rb * 16 + lg * 4 + r;
          if (R < c) {
            float* o = poscorr + (size_t)memL[R] * 4;
            o[0] = mp[r]; o[1] = sp[r]; o[2] = corr[r]; o[3] = (float)(c - 1);
          }
        }
      }
    }
  }
}

// ---- k2: per-row finish + fused final scalar via arrival counter ----------
__global__ __launch_bounds__(256) void k_rowsfinal(const float* __restrict__ part,
                                                   const float* __restrict__ poscorr,
                                                   float* __restrict__ bsum,
                                                   int* __restrict__ counter,
                                                   float* __restrict__ out) {
  const int bid = blockIdx.x;
  const int tid = threadIdx.x;
  const int l = tid & 63, w = tid >> 6;
  const int row = bid * 256 + tid;
  float sn = 0.f;
  #pragma unroll 8
  for (int q = 0; q < NT; ++q)
    sn += part[(size_t)q * NB + row];    // coalesced: 256 consecutive floats/q
  const float4 pc = *reinterpret_cast<const float4*>(poscorr + (size_t)row * 4);
  const int npi = (int)(pc.w + 0.5f);
  const bool valid = (npi > 0) && (npi < NB - 1);
  float val = 0.f;
  if (valid) {
    const float snn = fmaxf(sn - pc.z, 1e-30f);
    const float lp = LN2F * (pc.x + log2f(pc.y));
    const float ln_ = LN2F * log2f(snn);
    const float x = lp + ln_;
    val = fmaxf(x, 0.f) + log1pf(expf(-fabsf(x)));  // stable softplus
  }
  float cnt = valid ? 1.f : 0.f;
  val = wave_sum_f(val);
  cnt = wave_sum_f(cnt);
  __shared__ float svals[4], scnts[4];
  __shared__ int lastflag;
  if (l == 0) { svals[w] = val; scnts[w] = cnt; }
  __syncthreads();
  if (tid == 0) {
    bsum[bid * 2 + 0] = svals[0] + svals[1] + svals[2] + svals[3];
    bsum[bid * 2 + 1] = scnts[0] + scnts[1] + scnts[2] + scnts[3];
    __threadfence();                       // publish bsum device-wide
    const int prev = atomicAdd(counter, 1);
    lastflag = (prev == 31);
  }
  __syncthreads();
  if (lastflag && w == 0) {
    __threadfence();                       // acquire all blocks' bsum
    float s = 0.f, c = 0.f;
    if (l < 32) {
      volatile const float* vb = (volatile const float*)bsum;
      s = vb[l * 2];
      c = vb[l * 2 + 1];
    }
    s = wave_sum_f(s);
    c = wave_sum_f(c);
    if (l == 0) out[0] = s / fmaxf(c, 1.f);
  }
}

extern "C" void kernel_launch(void* const* d_in, const int* in_sizes, int n_in,
                              void* d_out, int out_size, void* d_ws, size_t ws_size,
                              hipStream_t stream) {
  const float* emb = (const float*)d_in[0];
  const int* labels = (const int*)d_in[1];
  float* out = (float*)d_out;
  char* ws = (char*)d_ws;

  float* part    = (float*)(ws + 0);         // 64*8192*4  = 2097152
  float* poscorr = (float*)(ws + 2097152);   // 8192*4*4   = 131072
  float* bsum    = (float*)(ws + 2228224);   // 256 B
  int*   counter = (int*)  (ws + 2228480);   // 8 B

  hipMemsetAsync(counter, 0, 8, stream);
  k_mainpos<<<NTRI + NLAB / 4, 256, 0, stream>>>(emb, labels, part, poscorr);
  k_rowsfinal<<<NB / 256, 256, 0, stream>>>(part, poscorr, bsum, counter, out);
}

// Round 16
// 41.600 us; speedup vs baseline: 1.3828x; 1.3828x over previous
//
#include <hip/hip_runtime.h>
#include <math.h>

#define NB 8192
#define ND 128
#define NT 64        // number of 128-row tiles
#define NTRI 2080    // NT*(NT+1)/2 upper-triangle tile pairs
#define TPB 4        // tile-pairs per block (pipelined)
#define NTRB (NTRI / TPB)   // 520 triangle blocks
#define NLAB 512
#define MAXM 64

typedef unsigned short u16;
typedef unsigned int u32;
typedef __attribute__((ext_vector_type(8))) short bf16x8;
typedef __attribute__((ext_vector_type(4))) float f32x4;

#define G2 369.3299304675746f         // gamma * log2(e)
#define NEG_C (-23.083120654223414f)  // -G2/16
#define SENT (-1e30f)
#define LN2F 0.6931471805599453f

static __device__ __forceinline__ void gload16(const void* g, void* l) {
  __builtin_amdgcn_global_load_lds(
      (const __attribute__((address_space(1))) u32*)g,
      (__attribute__((address_space(3))) u32*)l, 16, 0, 0);
}

static __device__ __forceinline__ float fexp2(float x) {
  return __builtin_amdgcn_exp2f(x);
}

static __device__ __forceinline__ u16 f2bf(float f) {
  u32 u = __float_as_uint(f);
  u32 r = (u + 0x7FFF + ((u >> 16) & 1)) >> 16;   // RNE
  return (u16)r;
}

static __device__ __forceinline__ float wave_sum_f(float v) {
  #pragma unroll
  for (int off = 1; off < 64; off <<= 1) v += __shfl_xor(v, off);
  return v;
}

static __device__ __forceinline__ int pre_(int t) { return t * NT - (t * (t - 1)) / 2; }
static __device__ __forceinline__ void trimap(int item, int& ti, int& tj) {
  int t = (int)((129.0f - sqrtf(16641.0f - 8.0f * (float)item)) * 0.5f);
  if (t > NT - 1) t = NT - 1;
  if (t < 0) t = 0;
  while (pre_(t + 1) <= item) ++t;
  while (pre_(t) > item) --t;
  ti = t;
  tj = t + (item - pre_(t));
}

// ---- k1: normalize rows + cast to bf16; reset arrival counter -------------
__global__ __launch_bounds__(512) void k_prep(const float* __restrict__ emb,
                                              u16* __restrict__ e,
                                              int* __restrict__ counters) {
  if (blockIdx.x == 0 && threadIdx.x < 2) counters[threadIdx.x] = 0;
  const int l = threadIdx.x & 63;
  const int w = threadIdx.x >> 6;
  const int row = blockIdx.x * 8 + w;
  const float2 v = reinterpret_cast<const float2*>(emb)[(size_t)row * 64 + l];
  float ss = wave_sum_f(v.x * v.x + v.y * v.y);
  const float inv = 1.0f / fmaxf(sqrtf(ss), 1e-12f);
  ushort2 o;
  o.x = f2bf(v.x * inv);
  o.y = f2bf(v.y * inv);
  reinterpret_cast<ushort2*>(e)[(size_t)row * 64 + l] = o;
}

// staging / A-load / compute as macros -> all register indices compile-time
#define LOADA(AF, ROW0)                                                         \
  _Pragma("unroll")                                                             \
  for (int m_ = 0; m_ < 2; ++m_) {                                              \
    _Pragma("unroll")                                                           \
    for (int ks_ = 0; ks_ < 4; ++ks_)                                           \
      AF[m_][ks_] = *(const bf16x8*)(e + (size_t)((ROW0) + w * 32 + m_ * 16 + lr_) * ND + ks_ * 32 + lg * 8); \
  }

#define STAGEB(BUFOFF, COL0, H)                                                 \
  _Pragma("unroll")                                                             \
  for (int i_ = 0; i_ < 4; ++i_) {                                              \
    const int rr_ = w * 16 + i_ * 4 + lg;                                       \
    gload16(e + (size_t)((COL0) + (H) * 64 + rr_) * ND + (lr_ ^ (rr_ & 15)) * 8, \
            S + (BUFOFF) + w * 4096 + i_ * 1024);                               \
  }

#define COMPUTE_HALF(AF, BUFOFF, H, ROW0, DIAG)                                 \
  {                                                                             \
    f32x4 acc[2][4];                                                            \
    _Pragma("unroll") for (int m_ = 0; m_ < 2; ++m_)                            \
      _Pragma("unroll") for (int n_ = 0; n_ < 4; ++n_)                          \
        _Pragma("unroll") for (int q_ = 0; q_ < 4; ++q_) acc[m_][n_][q_] = 0.f; \
    _Pragma("unroll") for (int ks_ = 0; ks_ < 4; ++ks_) {                       \
      const int kslot_ = (ks_ * 4 + lg) ^ lr_;                                  \
      bf16x8 bfr[4];                                                            \
      _Pragma("unroll") for (int n_ = 0; n_ < 4; ++n_)                          \
        bfr[n_] = *(const bf16x8*)(S + (BUFOFF) + (n_ * 16 + lr_) * 256 + kslot_ * 16); \
      _Pragma("unroll") for (int m_ = 0; m_ < 2; ++m_)                          \
        _Pragma("unroll") for (int n_ = 0; n_ < 4; ++n_)                        \
          acc[m_][n_] = __builtin_amdgcn_mfma_f32_16x16x32_bf16(AF[m_][ks_], bfr[n_], acc[m_][n_], 0, 0, 0); \
    }                                                                           \
    _Pragma("unroll") for (int m_ = 0; m_ < 2; ++m_) {                          \
      _Pragma("unroll") for (int n_ = 0; n_ < 4; ++n_) {                        \
        const bool dmn_ = (DIAG) && (w * 32 + m_ * 16 == (H) * 64 + n_ * 16);   \
        float scc_ = 0.f;                                                       \
        _Pragma("unroll") for (int j_ = 0; j_ < 4; ++j_) {                      \
          const float sv_ = acc[m_][n_][j_];                                    \
          float xn_ = fmaf(sv_ * sv_, G2, NEG_C);                               \
          xn_ = (sv_ > -0.25f) ? xn_ : 0.f;                                     \
          if (dmn_) xn_ = (lr_ == lg * 4 + j_) ? SENT : xn_;                    \
          const float ev_ = fexp2(xn_);                                         \
          sn[m_ * 4 + j_] += ev_;                                               \
          scc_ += ev_;                                                          \
        }                                                                       \
        colp[(H) * 4 + n_] += scc_;                                             \
      }                                                                         \
    }                                                                           \
  }

// ---- k2: pipelined triangle tiles (TPB items/block) | per-label pos -------
__global__ __launch_bounds__(256, 2) void k_mainpos(const u16* __restrict__ e,
                                                    const int* __restrict__ labels,
                                                    float* __restrict__ part,
                                                    float* __restrict__ poscorr) {
  __shared__ __align__(16) char S[34816];   // buf0(16K) buf1(16K) colbuf(2K)
  float* colbuf = (float*)(S + 32768);
  const int bid = blockIdx.x;
  const int tid = threadIdx.x;
  const int l = tid & 63;
  const int w = tid >> 6;
  const int lr_ = l & 15;
  const int lg = l >> 4;

  if (bid < NTRB) {
    // ============== pipelined upper-triangle items ==============
    const int item0 = bid * TPB;
    int ti, tj;
    trimap(item0, ti, tj);
    int row0 = ti * 128, col0 = tj * 128;
    bool diag = (ti == tj);

    bf16x8 afA[2][4], afB[2][4];
    LOADA(afA, row0);
    STAGEB(0, col0, 0);                  // item0 h0 -> buf0

    float sn[8], colp[8];
    #pragma unroll
    for (int q = 0; q < 8; ++q) { sn[q] = 0.f; colp[q] = 0.f; }

    __syncthreads();                     // buf0 landed
    STAGEB(16384, col0, 1);              // item0 h1 -> buf1 (flies during h0)

    #pragma unroll
    for (int i = 0; i < TPB; ++i) {
      int nti = 0, ntj = 0, nrow0 = 0, ncol0 = 0;
      bool ndiag = false;

      // phase (i, h0) from buf0
      if ((i & 1) == 0) { COMPUTE_HALF(afA, 0, 0, row0, diag); }
      else              { COMPUTE_HALF(afB, 0, 0, row0, diag); }
      __syncthreads();                   // (i,h1) staging landed in buf1
      if (i < TPB - 1) {                 // prefetch next item: B h0 + A frags
        trimap(item0 + i + 1, nti, ntj);
        nrow0 = nti * 128; ncol0 = ntj * 128; ndiag = (nti == ntj);
        STAGEB(0, ncol0, 0);             // hides behind (i,h1) compute
        if ((i & 1) == 0) { LOADA(afB, nrow0); }
        else              { LOADA(afA, nrow0); }
      }

      // phase (i, h1) from buf1
      if ((i & 1) == 0) { COMPUTE_HALF(afA, 16384, 1, row0, diag); }
      else              { COMPUTE_HALF(afB, 16384, 1, row0, diag); }

      // finish item i: row sums + colp reduce + colbuf publish
      #pragma unroll
      for (int q = 0; q < 8; ++q) {
        #pragma unroll
        for (int off = 1; off < 16; off <<= 1) sn[q] += __shfl_xor(sn[q], off);
      }
      if (lr_ == 0) {
        #pragma unroll
        for (int m = 0; m < 2; ++m)
          #pragma unroll
          for (int j = 0; j < 4; ++j) {
            const int row = row0 + w * 32 + m * 16 + lg * 4 + j;
            part[(size_t)tj * NB + row] = sn[m * 4 + j];
          }
      }
      #pragma unroll
      for (int q = 0; q < 8; ++q) {
        colp[q] += __shfl_xor(colp[q], 16);
        colp[q] += __shfl_xor(colp[q], 32);
      }
      if (!diag && l < 16) {
        #pragma unroll
        for (int q = 0; q < 8; ++q)
          colbuf[w * 128 + (q >> 2) * 64 + (q & 3) * 16 + lr_] = colp[q];
      }

      __syncthreads();                   // (i+1,h0) staging landed; colbuf ready
      if (i < TPB - 1) STAGEB(16384, ncol0, 1);   // hides behind (i+1,h0)
      if (!diag && tid < 128) {
        const float cs_ = colbuf[tid] + colbuf[128 + tid] +
                          colbuf[256 + tid] + colbuf[384 + tid];
        part[(size_t)ti * NB + col0 + tid] = cs_;
      }
      // rotate to next item
      #pragma unroll
      for (int q = 0; q < 8; ++q) { sn[q] = 0.f; colp[q] = 0.f; }
      ti = nti; tj = ntj; row0 = nrow0; col0 = ncol0; diag = ndiag;
    }
  } else {
    // ================= per-label positives + same-label correction =========
    int* lab = (int*)S;                        // 8192 ints = 32 KB
    for (int i = tid; i < NB / 4; i += 256)
      ((int4*)lab)[i] = ((const int4*)labels)[i];
    __syncthreads();

    const int L = (bid - NTRB) * 4 + w;        // one wave per label
    int* memL = (int*)(S + 32768) + w * MAXM;

    // build ordered member list via ballot rounds (ascending index order)
    int cnt = 0;
    for (int base = 0; base < NB; base += 64) {
      const int lv = lab[base + l];
      const unsigned long long mk = __ballot(lv == L);
      if (lv == L) {
        const int pos = __popcll(mk & ((1ull << l) - 1));
        if (cnt + pos < MAXM) memL[cnt + pos] = base + l;
      }
      cnt += __popcll(mk);
    }
    int c = cnt > MAXM ? MAXM : cnt;
    __syncthreads();   // memL visible across lanes of each wave

    const int nt = (c + 15) >> 4;
    for (int rb = 0; rb < nt; ++rb) {
      const int ri = rb * 16 + lr_;
      bf16x8 af[4];
      if (ri < c) {
        const u16* src = e + (size_t)memL[ri] * ND;
        #pragma unroll
        for (int ks = 0; ks < 4; ++ks)
          af[ks] = *(const bf16x8*)(src + ks * 32 + lg * 8);
      } else {
        #pragma unroll
        for (int ks = 0; ks < 4; ++ks) af[ks] = (bf16x8)0;
      }
      float corr[4], mp[4], sp[4];
      #pragma unroll
      for (int r = 0; r < 4; ++r) { corr[r] = 0.f; mp[r] = SENT; sp[r] = 0.f; }

      for (int cb = 0; cb < nt; ++cb) {
        const int ci = cb * 16 + lr_;
        bf16x8 bfr[4];
        if (ci < c) {
          const u16* src = e + (size_t)memL[ci] * ND;
          #pragma unroll
          for (int ks = 0; ks < 4; ++ks)
            bfr[ks] = *(const bf16x8*)(src + ks * 32 + lg * 8);
        } else {
          #pragma unroll
          for (int ks = 0; ks < 4; ++ks) bfr[ks] = (bf16x8)0;
        }
        f32x4 acc;
        #pragma unroll
        for (int r = 0; r < 4; ++r) acc[r] = 0.f;
        #pragma unroll
        for (int ks = 0; ks < 4; ++ks)
          acc = __builtin_amdgcn_mfma_f32_16x16x32_bf16(af[ks], bfr[ks], acc, 0, 0, 0);

        #pragma unroll
        for (int r = 0; r < 4; ++r) {
          const int R = rb * 16 + lg * 4 + r;
          const int Cj = cb * 16 + lr_;
          const bool ok = (R < c) && (Cj < c) && (R != Cj);
          const float sv = acc[r];
          float xn = fmaf(sv * sv, G2, NEG_C);
          xn = (sv > -0.25f) ? xn : 0.f;
          corr[r] += ok ? fexp2(xn) : 0.f;
          if (ok) {
            const float t1 = 1.25f - sv;
            const float xp = G2 * fmaxf(t1, 0.f) * (t1 - 0.5f);
            if (xp > mp[r]) { sp[r] = sp[r] * fexp2(mp[r] - xp) + 1.f; mp[r] = xp; }
            else sp[r] += fexp2(xp - mp[r]);
          }
        }
      }
      #pragma unroll
      for (int r = 0; r < 4; ++r) {
        #pragma unroll
        for (int off = 1; off < 16; off <<= 1) {
          corr[r] += __shfl_xor(corr[r], off);
          const float m2 = __shfl_xor(mp[r], off), s2 = __shfl_xor(sp[r], off);
          const float M = fmaxf(mp[r], m2);
          const float t1 = sp[r] * fexp2(mp[r] - M);  // exp2(-1e30)=0 for empties
          const float t2 = s2 * fexp2(m2 - M);
          mp[r] = M; sp[r] = t1 + t2;
        }
      }
      if (lr_ == 0) {
        #pragma unroll
        for (int r = 0; r < 4; ++r) {
          const int R = rb * 16 + lg * 4 + r;
          if (R < c) {
            float* o = poscorr + (size_t)memL[R] * 4;
            o[0] = mp[r]; o[1] = sp[r]; o[2] = corr[r]; o[3] = (float)(c - 1);
          }
        }
      }
    }
  }
}

// ---- k3: per-row finish + fused final scalar via arrival counter ----------
__global__ __launch_bounds__(256) void k_rowsfinal(const float* __restrict__ part,
                                                   const float* __restrict__ poscorr,
                                                   float* __restrict__ bsum,
                                                   int* __restrict__ counter,
                                                   float* __restrict__ out) {
  const int bid = blockIdx.x;
  const int tid = threadIdx.x;
  const int l = tid & 63, w = tid >> 6;
  const int row = bid * 256 + tid;
  float sn = 0.f;
  #pragma unroll 8
  for (int q = 0; q < NT; ++q)
    sn += part[(size_t)q * NB + row];    // coalesced: 256 consecutive floats/q
  const float4 pc = *reinterpret_cast<const float4*>(poscorr + (size_t)row * 4);
  const int npi = (int)(pc.w + 0.5f);
  const bool valid = (npi > 0) && (npi < NB - 1);
  float val = 0.f;
  if (valid) {
    const float snn = fmaxf(sn - pc.z, 1e-30f);
    const float lp = LN2F * (pc.x + log2f(pc.y));
    const float ln_ = LN2F * log2f(snn);
    const float x = lp + ln_;
    val = fmaxf(x, 0.f) + log1pf(expf(-fabsf(x)));  // stable softplus
  }
  float cnt = valid ? 1.f : 0.f;
  val = wave_sum_f(val);
  cnt = wave_sum_f(cnt);
  __shared__ float svals[4], scnts[4];
  __shared__ int lastflag;
  if (l == 0) { svals[w] = val; scnts[w] = cnt; }
  __syncthreads();
  if (tid == 0) {
    bsum[bid * 2 + 0] = svals[0] + svals[1] + svals[2] + svals[3];
    bsum[bid * 2 + 1] = scnts[0] + scnts[1] + scnts[2] + scnts[3];
    __threadfence();                       // publish bsum device-wide
    const int prev = atomicAdd(counter, 1);
    lastflag = (prev == 31);
  }
  __syncthreads();
  if (lastflag && w == 0) {
    __threadfence();                       // acquire all blocks' bsum
    float s = 0.f, c = 0.f;
    if (l < 32) {
      volatile const float* vb = (volatile const float*)bsum;
      s = vb[l * 2];
      c = vb[l * 2 + 1];
    }
    s = wave_sum_f(s);
    c = wave_sum_f(c);
    if (l == 0) out[0] = s / fmaxf(c, 1.f);
  }
}

extern "C" void kernel_launch(void* const* d_in, const int* in_sizes, int n_in,
                              void* d_out, int out_size, void* d_ws, size_t ws_size,
                              hipStream_t stream) {
  const float* emb = (const float*)d_in[0];
  const int* labels = (const int*)d_in[1];
  float* out = (float*)d_out;
  char* ws = (char*)d_ws;

  float* part    = (float*)(ws + 0);         // 64*8192*4  = 2097152
  float* poscorr = (float*)(ws + 2097152);   // 8192*4*4   = 131072
  u16*   ebf     = (u16*)  (ws + 2228224);   // 8192*128*2 = 2097152
  float* bsum    = (float*)(ws + 4325376);   // 256 B
  int*   counter = (int*)  (ws + 4325632);   // 8 B

  k_prep<<<NB / 8, 512, 0, stream>>>(emb, ebf, counter);
  k_mainpos<<<NTRB + NLAB / 4, 256, 0, stream>>>(ebf, labels, part, poscorr);
  k_rowsfinal<<<NB / 256, 256, 0, stream>>>(part, poscorr, bsum, counter, out);
}